// Round 4
// baseline (452.772 us; speedup 1.0000x reference)
//
#include <hip/hip_runtime.h>

#define HH 128
#define WW 128
#define HW (HH*WW)

// ---- ws layout (float offsets) ----
#define O_H1   0u         // (4,64,128,128) f32
#define O_H2   4194304u   // (4,32,128,128) f32
#define O_WO2T 6291456u   // [ci][k][co20] 64*9*20 = 11520
#define O_W2T  6302976u   // [n][ci][co32] 9*64*32 = 18432
#define O_WO3T 6321408u   // [ci][k][co20] 32*9*20 = 5760
#define O_W3T  6327168u   // [n][ci][co4]  9*32*4  = 1152
#define O_BO2  6328320u
#define O_B2   6328352u
#define O_BO3  6328384u
#define O_B3   6328416u

typedef unsigned short u16;
typedef unsigned int   u32;
typedef unsigned long long u64;

__device__ __forceinline__ float bf2f(u16 h) {
    return __uint_as_float(((u32)h) << 16);
}
__device__ __forceinline__ u16 f2bf(float f) {   // round-to-nearest-even
    u32 u = __float_as_uint(f);
    return (u16)((u + 0x7FFFu + ((u >> 16) & 1u)) >> 16);
}
__device__ __forceinline__ float ldm(const void* p, int i, bool bf) {
    return bf ? bf2f(((const u16*)p)[i]) : ((const float*)p)[i];
}
// wave-uniform dtype flag from first 64 words of x (see round-2 notes)
__device__ __forceinline__ bool wave_flag(const u32* xu) {
    u32 w = xu[threadIdx.x & 63];
    u32 lo = w & 0xFFFFu;
    u32 e = (lo >> 7) & 0xFFu;
    bool ok = (lo != 0u) && (e >= 100u) && (e <= 140u);
    return __popcll(__ballot(ok)) > 32;
}

// ---- weights -> f32, transposed/padded ----
__global__ __launch_bounds__(256) void prep_weights(
        const u32* xu,
        const void* wo2, const void* bo2, const void* w2, const void* b2,
        const void* wo3, const void* bo3, const void* w3, const void* b3,
        float* ws) {
    bool bf = wave_flag(xu);
    int i = blockIdx.x * 256 + threadIdx.x;
    if (i < 11520) {                     // wo2t [ci][k][co20]
        int co = i % 20, k = (i / 20) % 9, ci = i / 180;
        ws[O_WO2T + i] = (co < 18) ? ldm(wo2, (co * 64 + ci) * 9 + k, bf) : 0.f;
    }
    if (i < 18432) {                     // w2t [n][ci][co32]
        int co = i & 31, ci = (i >> 5) & 63, n = i / 2048;
        ws[O_W2T + i] = ldm(w2, (co * 64 + ci) * 9 + n, bf);
    }
    if (i < 5760) {                      // wo3t [ci][k][co20]
        int co = i % 20, k = (i / 20) % 9, ci = i / 180;
        ws[O_WO3T + i] = (co < 18) ? ldm(wo3, (co * 32 + ci) * 9 + k, bf) : 0.f;
    }
    if (i < 1152) {                      // w3t [n][ci][co4]
        int co = i & 3, ci = (i >> 2) & 31, n = i / 128;
        ws[O_W3T + i] = ldm(w3, (co * 32 + ci) * 9 + n, bf);
    }
    if (i < 18) ws[O_BO2 + i] = ldm(bo2, i, bf);
    if (i < 32) ws[O_B2 + i]  = ldm(b2, i, bf);
    if (i < 18) ws[O_BO3 + i] = ldm(bo3, i, bf);
    if (i < 4)  ws[O_B3 + i]  = ldm(b3, i, bf);
}

// conv1: x (B,1,H,W) -> h1 (B,64,H,W) f32, relu, pad 1. 4 co per thread.
__global__ __launch_bounds__(256) void conv1_kernel(
        const u32* xu, const void* x, const void* w, const void* bias,
        float* __restrict__ out) {
    bool bf = wave_flag(xu);
    int idx = blockIdx.x * 256 + threadIdx.x;     // 4*16*128*128 threads
    int xw = idx & 127; int t = idx >> 7;
    int yh = t & 127;   t >>= 7;
    int cg = t & 15;    int b = t >> 4;
    float xv[9];
    #pragma unroll
    for (int ky = 0; ky < 3; ++ky) {
        int yy = yh + ky - 1;
        #pragma unroll
        for (int kx = 0; kx < 3; ++kx) {
            int xx = xw + kx - 1;
            xv[ky * 3 + kx] =
                ((unsigned)yy < 128u && (unsigned)xx < 128u)
                    ? ldm(x, b * HW + yy * WW + xx, bf) : 0.f;
        }
    }
    #pragma unroll
    for (int j = 0; j < 4; ++j) {
        int co = cg * 4 + j;
        float acc = ldm(bias, co, bf);
        #pragma unroll
        for (int k = 0; k < 9; ++k)
            acc = fmaf(ldm(w, co * 9 + k, bf), xv[k], acc);
        out[((size_t)(b * 64 + co) * HH + yh) * WW + xw] = fmaxf(acc, 0.f);
    }
}

// =====================================================================
// Fused: 3x3 pad-1 offset-conv (CIN->18) + deform-sample + stride-3
// conv (CIN->COUT). Block = 64-px half row x 4 ci-groups. grid 1024.
// =====================================================================
template<int CIN, int COUT, bool FINAL>
__global__ __launch_bounds__(256, 4) void fused_kernel(
        const float* __restrict__ feat,
        const float* __restrict__ wo, const float* __restrict__ bo,
        const float* __restrict__ wd, const float* __restrict__ bd,
        const u32* __restrict__ xu,
        float* __restrict__ outf, u32* __restrict__ outb) {
    constexpr int CH = CIN / 4;                 // channels per group
    constexpr int UNION = (COUT == 32) ? 4224 : 2880;
    __shared__ float smem[UNION + 64 * 19];
    float* offb = smem + UNION;

    bool bf = FINAL ? wave_flag(xu) : false;
    int tid = threadIdx.x;
    int pix = tid & 63;
    int g   = tid >> 6;
    int gs  = __builtin_amdgcn_readfirstlane(g);
    int bid = blockIdx.x;
    int hx = bid & 1, yh = (bid >> 1) & 127, b = bid >> 8;
    int xw = hx * 64 + pix;
    int bx = hx * 64 - 4;
    float4 z4; z4.x = z4.y = z4.z = z4.w = 0.f;

    // ---- stage map A: 4 groups x 3 rows x 72 cols, 216 float4 slots ----
    int jA = tid;                // valid < 216
    int gA = jA / 54, remA = jA % 54;
    int rowA = remA / 18, c4A = remA % 18;
    int gyA = yh - 1 + rowA, gcA = bx + 4 * c4A;
    bool vA = (tid < 216) && ((unsigned)gyA < 128u) && ((unsigned)gcA < 128u);
    const float* spA = feat + ((size_t)(b * CIN + gA * CH) * HW + gyA * WW + gcA);
    int dA = gA * 216 + rowA * 72 + 4 * c4A;

    // ---- stage map B: 4 groups x 5 rows x 72 cols, 360 float4 slots ----
    int j0 = tid, j1 = tid + 256;
    int g0 = j0 / 90, rem0 = j0 % 90;
    int row0 = rem0 / 18, c40 = rem0 % 18;
    int gy0 = yh - 2 + row0, gc0 = bx + 4 * c40;
    bool v0 = ((unsigned)gy0 < 128u) && ((unsigned)gc0 < 128u);
    const float* sp0 = feat + ((size_t)(b * CIN + g0 * CH) * HW + gy0 * WW + gc0);
    int d0 = g0 * 360 + row0 * 72 + 4 * c40;
    int g1 = j1 / 90, rem1 = j1 % 90;
    int row1 = rem1 / 18, c41 = rem1 % 18;
    int gy1 = yh - 2 + row1, gc1 = bx + 4 * c41;
    bool v1 = (tid < 104) && ((unsigned)gy1 < 128u) && ((unsigned)gc1 < 128u);
    const float* sp1 = feat + ((size_t)(b * CIN + g1 * CH) * HW + gy1 * WW + gc1);
    int d1 = g1 * 360 + row1 * 72 + 4 * c41;

    // ================= phase A: offset conv =================
    {
        float4 a0 = vA ? *(const float4*)spA : z4;
        if (tid < 216) *(float4*)&smem[dA] = a0;
    }
    __syncthreads();

    float acc[20];
    #pragma unroll
    for (int c = 0; c < 20; ++c) acc[c] = (g == 0 && c < 18) ? bo[c] : 0.f;

    #pragma unroll 1
    for (int r = 0; r < CH; ++r) {
        float4 n0 = z4;
        if (r + 1 < CH && vA)
            n0 = *(const float4*)(spA + (size_t)(r + 1) * HW);
        const float* L = smem + (r & 1) * 864 + gs * 216;
        float v[9];
        #pragma unroll
        for (int ky = 0; ky < 3; ++ky) {
            const float* Lr = L + ky * 72 + pix + 3;
            v[ky * 3 + 0] = Lr[0];
            v[ky * 3 + 1] = Lr[1];
            v[ky * 3 + 2] = Lr[2];
        }
        const float* wr = wo + (size_t)(gs * CH + r) * 180;
        #pragma unroll
        for (int k = 0; k < 9; ++k) {
            __builtin_amdgcn_sched_barrier(0);
            #pragma unroll
            for (int q = 0; q < 5; ++q) {
                float4 wv = *(const float4*)(wr + k * 20 + q * 4);
                acc[q * 4 + 0] = fmaf(v[k], wv.x, acc[q * 4 + 0]);
                acc[q * 4 + 1] = fmaf(v[k], wv.y, acc[q * 4 + 1]);
                acc[q * 4 + 2] = fmaf(v[k], wv.z, acc[q * 4 + 2]);
                acc[q * 4 + 3] = fmaf(v[k], wv.w, acc[q * 4 + 3]);
            }
        }
        if (r + 1 < CH && tid < 216)
            *(float4*)&smem[((r + 1) & 1) * 864 + dA] = n0;
        __syncthreads();
    }

    // 4-way reduce -> offb[pix*19 + co]
    if (g >= 2) {
        #pragma unroll
        for (int c = 0; c < 18; ++c) smem[(g - 2) * 1344 + pix * 21 + c] = acc[c];
    }
    __syncthreads();
    if (g < 2) {
        #pragma unroll
        for (int c = 0; c < 18; ++c) acc[c] += smem[g * 1344 + pix * 21 + c];
    }
    __syncthreads();
    if (g == 1) {
        #pragma unroll
        for (int c = 0; c < 18; ++c) smem[pix * 21 + c] = acc[c];
    }
    __syncthreads();
    if (g == 0) {
        #pragma unroll
        for (int c = 0; c < 18; ++c) offb[pix * 19 + c] = acc[c] + smem[pix * 21 + c];
    }
    __syncthreads();

    // ================= geometry + phase-B r0 stage (overlapped) ==========
    float4 s0 = v0 ? *(const float4*)sp0 : z4;
    float4 s1 = v1 ? *(const float4*)sp1 : z4;

    float wyA[9], wxA[9];
    int pk[9];
    #pragma unroll
    for (int n = 0; n < 9; ++n) {
        float py = offb[pix * 19 + n]     + (float)(n / 3 - 1 + yh);
        float px = offb[pix * 19 + 9 + n] + (float)(n % 3 - 1) + (float)xw;
        py = fminf(fmaxf(py, 0.f), 127.f);
        px = fminf(fmaxf(px, 0.f), 127.f);
        float y0f = floorf(py), x0f = floorf(px);
        int y0 = (int)y0f, x0 = (int)x0f;
        int dy = (y0 < 127) ? 1 : 0;
        int dx = (x0 < 127) ? 1 : 0;
        wyA[n] = py - y0f;
        wxA[n] = px - x0f;
        int slot = y0 - yh + 2;
        int cix  = x0 - bx;
        bool inw = (slot >= 0) && (slot + dy <= 4) && (cix >= 0) && (cix + dx < 72);
        int a = slot * 72 + cix;
        pk[n] = (inw ? ((1 << 11) | a) : 0) | (dx << 9) | (dy << 10)
              | (x0 << 12) | (y0 << 19);
    }

    *(float4*)&smem[d0] = s0;
    if (tid < 104) *(float4*)&smem[d1] = s1;
    __syncthreads();

    // ================= phase B: deform + stride-3 conv =================
    float accB[COUT];
    #pragma unroll
    for (int c = 0; c < COUT; ++c) accB[c] = (g == 0) ? bd[c] : 0.f;
    const float* fbg = feat + (size_t)(b * CIN + gs * CH) * HW;

    #pragma unroll 1
    for (int r = 0; r < CH; ++r) {
        float4 n0 = z4, n1 = z4;
        if (r + 1 < CH) {
            if (v0) n0 = *(const float4*)(sp0 + (size_t)(r + 1) * HW);
            if (v1) n1 = *(const float4*)(sp1 + (size_t)(r + 1) * HW);
        }
        const float* L = smem + (r & 1) * 1440 + gs * 360;
        #pragma unroll
        for (int n = 0; n < 9; ++n) {
            __builtin_amdgcn_sched_barrier(0);
            int p = pk[n];
            float wy = wyA[n], wx = wxA[n];
            int dxo = (p >> 9) & 1;
            float v;
            if (p & (1 << 11)) {
                int a = p & 511;
                int dyo = ((p >> 10) & 1) * 72;
                float p00 = L[a], p01 = L[a + dxo];
                float p10 = L[a + dyo], p11 = L[a + dyo + dxo];
                float top = fmaf(wx, p01 - p00, p00);
                float bot = fmaf(wx, p11 - p10, p10);
                v = fmaf(wy, bot - top, top);
            } else {   // out-of-window fallback (general offsets)
                int x0 = (p >> 12) & 127, y0 = (p >> 19) & 127;
                const float* fp = fbg + (size_t)r * HW + y0 * WW + x0;
                int dyo = ((p >> 10) & 1) * WW;
                float p00 = fp[0], p01 = fp[dxo];
                float p10 = fp[dyo], p11 = fp[dyo + dxo];
                float top = fmaf(wx, p01 - p00, p00);
                float bot = fmaf(wx, p11 - p10, p10);
                v = fmaf(wy, bot - top, top);
            }
            const float* wr = wd + (size_t)(n * CIN + gs * CH + r) * COUT;
            #pragma unroll
            for (int q = 0; q < COUT / 4; ++q) {
                float4 wv = *(const float4*)(wr + q * 4);
                accB[q * 4 + 0] = fmaf(v, wv.x, accB[q * 4 + 0]);
                accB[q * 4 + 1] = fmaf(v, wv.y, accB[q * 4 + 1]);
                accB[q * 4 + 2] = fmaf(v, wv.z, accB[q * 4 + 2]);
                accB[q * 4 + 3] = fmaf(v, wv.w, accB[q * 4 + 3]);
            }
        }
        if (r + 1 < CH) {
            int d = ((r + 1) & 1) * 1440;
            *(float4*)&smem[d + d0] = n0;
            if (tid < 104) *(float4*)&smem[d + d1] = n1;
        }
        __syncthreads();
    }

    // 4-way reduce + write
    constexpr int PS = COUT + 1;
    if (g >= 2) {
        #pragma unroll
        for (int c = 0; c < COUT; ++c) smem[(g - 2) * 64 * PS + pix * PS + c] = accB[c];
    }
    __syncthreads();
    if (g < 2) {
        #pragma unroll
        for (int c = 0; c < COUT; ++c) accB[c] += smem[g * 64 * PS + pix * PS + c];
    }
    __syncthreads();
    if (g == 1) {
        #pragma unroll
        for (int c = 0; c < COUT; ++c) smem[pix * PS + c] = accB[c];
    }
    __syncthreads();
    if (g == 0) {
        #pragma unroll
        for (int c = 0; c < COUT; ++c) accB[c] += smem[pix * PS + c];
        if (!FINAL) {
            #pragma unroll
            for (int c = 0; c < COUT; ++c)
                outf[((size_t)(b * COUT + c) * HH + yh) * WW + xw] =
                    fmaxf(accB[c], 0.f);
        } else {
            if (bf) {
                u32 p0 = ((u32)f2bf(accB[1]) << 16) | (u32)f2bf(accB[0]);
                u32 p1 = ((u32)f2bf(accB[3]) << 16) | (u32)f2bf(accB[2]);
                outb[(size_t)(b * 256 + 2 * yh) * 128 + xw]       = p0;
                outb[(size_t)(b * 256 + 2 * yh + 1) * 128 + xw]   = p1;
            } else {
                float* o = outf;
                size_t r0 = (size_t)(b * 256 + 2 * yh) * 256 + 2 * xw;
                o[r0]       = accB[0];
                o[r0 + 1]   = accB[1];
                o[r0 + 256] = accB[2];
                o[r0 + 257] = accB[3];
            }
        }
    }
}

extern "C" void kernel_launch(void* const* d_in, const int* in_sizes, int n_in,
                              void* d_out, int out_size, void* d_ws, size_t ws_size,
                              hipStream_t stream) {
    float* ws = (float*)d_ws;
    const u32* xu = (const u32*)d_in[0];
    prep_weights<<<72, 256, 0, stream>>>(xu, d_in[3], d_in[4], d_in[5], d_in[6],
                                         d_in[7], d_in[8], d_in[9], d_in[10], ws);
    conv1_kernel<<<4096, 256, 0, stream>>>(xu, d_in[0], d_in[1], d_in[2], ws + O_H1);
    fused_kernel<64, 32, false><<<1024, 256, 0, stream>>>(
        ws + O_H1, ws + O_WO2T, ws + O_BO2, ws + O_W2T, ws + O_B2,
        xu, ws + O_H2, nullptr);
    fused_kernel<32, 4, true><<<1024, 256, 0, stream>>>(
        ws + O_H2, ws + O_WO3T, ws + O_BO3, ws + O_W3T, ws + O_B3,
        xu, (float*)d_out, (u32*)d_out);
}

// Round 5
// 367.792 us; speedup vs baseline: 1.2311x; 1.2311x over previous
//
#include <hip/hip_runtime.h>

#define HH 128
#define WW 128
#define HW (HH*WW)

// ---- ws layout (float offsets) ----
#define O_H1   0u         // (4,64,128,128) f32
#define O_H2   4194304u   // (4,32,128,128) f32
#define O_WO2T 6291456u   // [ci][k][co20] 64*9*20 = 11520
#define O_W2T  6302976u   // [g][n][ci][co8] 4*9*64*8 = 18432
#define O_WO3T 6321408u   // [ci][k][co20] 32*9*20 = 5760
#define O_W3T  6327168u   // [n][ci][co4]  9*32*4  = 1152
#define O_BO2  6328320u
#define O_B2   6328352u
#define O_BO3  6328384u
#define O_B3   6328416u

typedef unsigned short u16;
typedef unsigned int   u32;

__device__ __forceinline__ float bf2f(u16 h) {
    return __uint_as_float(((u32)h) << 16);
}
__device__ __forceinline__ u16 f2bf(float f) {   // round-to-nearest-even
    u32 u = __float_as_uint(f);
    return (u16)((u + 0x7FFFu + ((u >> 16) & 1u)) >> 16);
}
__device__ __forceinline__ float ldm(const void* p, int i, bool bf) {
    return bf ? bf2f(((const u16*)p)[i]) : ((const float*)p)[i];
}
// wave-uniform dtype flag from first 64 words of x (see round-2 notes)
__device__ __forceinline__ bool wave_flag(const u32* xu) {
    u32 w = xu[threadIdx.x & 63];
    u32 lo = w & 0xFFFFu;
    u32 e = (lo >> 7) & 0xFFu;
    bool ok = (lo != 0u) && (e >= 100u) && (e <= 140u);
    return __popcll(__ballot(ok)) > 32;
}

// ---- weights -> f32, transposed/padded ----
__global__ __launch_bounds__(256) void prep_weights(
        const u32* xu,
        const void* wo2, const void* bo2, const void* w2, const void* b2,
        const void* wo3, const void* bo3, const void* w3, const void* b3,
        float* ws) {
    bool bf = wave_flag(xu);
    int i = blockIdx.x * 256 + threadIdx.x;
    if (i < 11520) {                     // wo2t [ci][k][co20]
        int co = i % 20, k = (i / 20) % 9, ci = i / 180;
        ws[O_WO2T + i] = (co < 18) ? ldm(wo2, (co * 64 + ci) * 9 + k, bf) : 0.f;
    }
    if (i < 18432) {                     // w2t [g][n][ci][co8]
        int c8 = i & 7, ci = (i >> 3) & 63, n = (i >> 9) % 9, g = i / 4608;
        int co = g * 8 + c8;
        ws[O_W2T + i] = ldm(w2, (co * 64 + ci) * 9 + n, bf);
    }
    if (i < 5760) {                      // wo3t [ci][k][co20]
        int co = i % 20, k = (i / 20) % 9, ci = i / 180;
        ws[O_WO3T + i] = (co < 18) ? ldm(wo3, (co * 32 + ci) * 9 + k, bf) : 0.f;
    }
    if (i < 1152) {                      // w3t [n][ci][co4]
        int co = i & 3, ci = (i >> 2) & 31, n = i / 128;
        ws[O_W3T + i] = ldm(w3, (co * 32 + ci) * 9 + n, bf);
    }
    if (i < 18) ws[O_BO2 + i] = ldm(bo2, i, bf);
    if (i < 32) ws[O_B2 + i]  = ldm(b2, i, bf);
    if (i < 18) ws[O_BO3 + i] = ldm(bo3, i, bf);
    if (i < 4)  ws[O_B3 + i]  = ldm(b3, i, bf);
}

// conv1: x (B,1,H,W) -> h1 (B,64,H,W) f32, relu, pad 1. 4 co per thread.
__global__ __launch_bounds__(256) void conv1_kernel(
        const u32* xu, const void* x, const void* w, const void* bias,
        float* __restrict__ out) {
    bool bf = wave_flag(xu);
    int idx = blockIdx.x * 256 + threadIdx.x;
    int xw = idx & 127; int t = idx >> 7;
    int yh = t & 127;   t >>= 7;
    int cg = t & 15;    int b = t >> 4;
    float xv[9];
    #pragma unroll
    for (int ky = 0; ky < 3; ++ky) {
        int yy = yh + ky - 1;
        #pragma unroll
        for (int kx = 0; kx < 3; ++kx) {
            int xx = xw + kx - 1;
            xv[ky * 3 + kx] =
                ((unsigned)yy < 128u && (unsigned)xx < 128u)
                    ? ldm(x, b * HW + yy * WW + xx, bf) : 0.f;
        }
    }
    #pragma unroll
    for (int j = 0; j < 4; ++j) {
        int co = cg * 4 + j;
        float acc = ldm(bias, co, bf);
        #pragma unroll
        for (int k = 0; k < 9; ++k)
            acc = fmaf(ldm(w, co * 9 + k, bf), xv[k], acc);
        out[((size_t)(b * 64 + co) * HH + yh) * WW + xw] = fmaxf(acc, 0.f);
    }
}

// =====================================================================
// fused_mid: offset-conv(64->18) + deform + stride-3 conv(64->32) + relu
// Block = 64-px half-row. Phase A: 4 groups split ci (16 each).
// Phase B: 4 groups split co (8 each); samples shared via LDS vbuf.
// =====================================================================
__global__ __launch_bounds__(256) void fused_mid(
        const float* __restrict__ feat,
        const float* __restrict__ wo, const float* __restrict__ bo,
        const float* __restrict__ wd, const float* __restrict__ bd,
        float* __restrict__ out) {
    __shared__ float smem[7424];   // win[0,2880) | vbuf/red[2880,6208) | offb[6208,7424)
    constexpr int VB = 2880, OFB = 6208;
    int tid = threadIdx.x;
    int pix = tid & 63, g = tid >> 6;
    int gs = __builtin_amdgcn_readfirstlane(g);
    int bid = blockIdx.x;
    int hx = bid & 1, yh = (bid >> 1) & 127, b = bid >> 8;
    int xw = hx * 64 + pix, bx = hx * 64 - 4;
    float4 z4; z4.x = z4.y = z4.z = z4.w = 0.f;

    // ---- A staging: 216 slots = 4 ci-groups x 3 rows x 18 col4 ----
    int gA = tid / 54, remA = tid % 54;
    int rowA = remA / 18, c4A = remA % 18;
    int gyA = yh - 1 + rowA, gcA = bx + 4 * c4A;
    bool vA = (tid < 216) && ((unsigned)gyA < 128u) && ((unsigned)gcA < 128u);
    const float* spA = feat + ((size_t)(b * 64 + gA * 16) * HW + gyA * WW + gcA);
    int dA = 4 * tid;

    { float4 a0 = vA ? *(const float4*)spA : z4;
      if (tid < 216) *(float4*)&smem[dA] = a0; }
    __syncthreads();

    // ================= phase A: offset conv (ci-split) =================
    float acc[20];
    #pragma unroll
    for (int c = 0; c < 20; ++c) acc[c] = (g == 0 && c < 18) ? bo[c] : 0.f;

    #pragma unroll 1
    for (int r = 0; r < 16; ++r) {
        float4 n0 = z4;
        if (r + 1 < 16 && vA) n0 = *(const float4*)(spA + (size_t)(r + 1) * HW);
        const float* L = smem + (r & 1) * 864 + gs * 216;
        float v[9];
        #pragma unroll
        for (int ky = 0; ky < 3; ++ky) {
            const float* Lr = L + ky * 72 + pix + 3;
            v[ky * 3 + 0] = Lr[0];
            v[ky * 3 + 1] = Lr[1];
            v[ky * 3 + 2] = Lr[2];
        }
        const float* wr = wo + (size_t)(gs * 16 + r) * 180;
        #pragma unroll
        for (int k = 0; k < 9; ++k) {
            __builtin_amdgcn_sched_barrier(0);
            #pragma unroll
            for (int q = 0; q < 5; ++q) {
                float4 wv = *(const float4*)(wr + k * 20 + q * 4);
                acc[q * 4 + 0] = fmaf(v[k], wv.x, acc[q * 4 + 0]);
                acc[q * 4 + 1] = fmaf(v[k], wv.y, acc[q * 4 + 1]);
                acc[q * 4 + 2] = fmaf(v[k], wv.z, acc[q * 4 + 2]);
                acc[q * 4 + 3] = fmaf(v[k], wv.w, acc[q * 4 + 3]);
            }
        }
        if (r + 1 < 16 && tid < 216)
            *(float4*)&smem[((r + 1) & 1) * 864 + dA] = n0;
        __syncthreads();
    }
    // 4-way reduce -> offb
    if (g >= 2) {
        #pragma unroll
        for (int c = 0; c < 18; ++c) smem[VB + (g - 2) * 1344 + pix * 21 + c] = acc[c];
    }
    __syncthreads();
    if (g < 2) {
        #pragma unroll
        for (int c = 0; c < 18; ++c) acc[c] += smem[VB + g * 1344 + pix * 21 + c];
    }
    __syncthreads();
    if (g == 1) {
        #pragma unroll
        for (int c = 0; c < 18; ++c) smem[VB + pix * 21 + c] = acc[c];
    }
    __syncthreads();
    if (g == 0) {
        #pragma unroll
        for (int c = 0; c < 18; ++c)
            smem[OFB + pix * 19 + c] = acc[c] + smem[VB + pix * 21 + c];
    }
    __syncthreads();

    // ================= geometry =================
    float wyA[9], wxA[9];
    int pk[9];
    #pragma unroll
    for (int n = 0; n < 9; ++n) {
        float py = smem[OFB + pix * 19 + n]     + (float)(n / 3 - 1 + yh);
        float px = smem[OFB + pix * 19 + 9 + n] + (float)(n % 3 - 1 + xw);
        py = fminf(fmaxf(py, 0.f), 127.f);
        px = fminf(fmaxf(px, 0.f), 127.f);
        float y0f = floorf(py), x0f = floorf(px);
        int y0 = (int)y0f, x0 = (int)x0f;
        int dy = (y0 < 127) ? 1 : 0;
        int dx = (x0 < 127) ? 1 : 0;
        wyA[n] = py - y0f;
        wxA[n] = px - x0f;
        int slot = y0 - yh + 2;
        int cix  = x0 - bx;
        bool inw = (slot >= 0) && (slot + dy <= 4) && (cix >= 0) && (cix + dx < 72);
        int a = slot * 72 + cix;
        pk[n] = (inw ? ((1 << 11) | a) : 0) | (dx << 9) | (dy << 10)
              | (x0 << 12) | (y0 << 19);
    }

    // ---- B staging: 360 slots = 4 round-channels x 5 rows x 18 col4 ----
    int ch0 = tid / 90, rem0 = tid % 90;
    int row0 = rem0 / 18, c40 = rem0 % 18;
    int gy0 = yh - 2 + row0, gc0 = bx + 4 * c40;
    bool v0 = ((unsigned)gy0 < 128u) && ((unsigned)gc0 < 128u);
    const float* sp0 = feat + ((size_t)(b * 64 + ch0) * HW + gy0 * WW + gc0);
    int d0 = 4 * tid;
    int j1 = tid + 256;
    int ch1 = j1 / 90, rem1 = j1 % 90;
    int row1 = rem1 / 18, c41 = rem1 % 18;
    int gy1 = yh - 2 + row1, gc1 = bx + 4 * c41;
    bool v1 = (tid < 104) && ((unsigned)gy1 < 128u) && ((unsigned)gc1 < 128u);
    const float* sp1 = feat + ((size_t)(b * 64 + ch1) * HW + gy1 * WW + gc1);
    int d1 = 4 * j1;

    { float4 s0 = v0 ? *(const float4*)sp0 : z4;
      float4 s1 = v1 ? *(const float4*)sp1 : z4;
      *(float4*)&smem[d0] = s0;
      if (tid < 104) *(float4*)&smem[d1] = s1; }
    __syncthreads();

    // ================= phase B: deform + conv (co-split) =================
    float accB[8];
    #pragma unroll
    for (int c = 0; c < 8; ++c) accB[c] = bd[gs * 8 + c];

    #pragma unroll 1
    for (int r = 0; r < 16; ++r) {
        float4 n0 = z4, n1 = z4;
        if (r + 1 < 16) {
            if (v0) n0 = *(const float4*)(sp0 + (size_t)(r + 1) * 4 * HW);
            if (v1) n1 = *(const float4*)(sp1 + (size_t)(r + 1) * 4 * HW);
        }
        // B1: sample my channel (c = r*4+g) at all 9 taps -> vbuf
        {
            const float* Lg = smem + (r & 1) * 1440 + gs * 360;
            const float* fbg = feat + (size_t)(b * 64 + r * 4 + gs) * HW;
            #pragma unroll
            for (int n = 0; n < 9; ++n) {
                int p = pk[n];
                float wy = wyA[n], wx = wxA[n];
                int dxo = (p >> 9) & 1;
                float val;
                if (p & (1 << 11)) {
                    int a = p & 511;
                    int dyo = ((p >> 10) & 1) * 72;
                    float p00 = Lg[a], p01 = Lg[a + dxo];
                    float p10 = Lg[a + dyo], p11 = Lg[a + dyo + dxo];
                    float top = fmaf(wx, p01 - p00, p00);
                    float bot = fmaf(wx, p11 - p10, p10);
                    val = fmaf(wy, bot - top, top);
                } else {       // out-of-window fallback (general offsets)
                    int x0 = (p >> 12) & 127, y0 = (p >> 19) & 127;
                    const float* fp = fbg + y0 * WW + x0;
                    int dyo = ((p >> 10) & 1) * WW;
                    float p00 = fp[0], p01 = fp[dxo];
                    float p10 = fp[dyo], p11 = fp[dyo + dxo];
                    float top = fmaf(wx, p01 - p00, p00);
                    float bot = fmaf(wx, p11 - p10, p10);
                    val = fmaf(wy, bot - top, top);
                }
                smem[VB + (gs * 64 + pix) * 13 + n] = val;
            }
        }
        __syncthreads();
        // B2: each group FMAs its 8-co slice over the 4 channels
        #pragma unroll
        for (int ch = 0; ch < 4; ++ch) {
            __builtin_amdgcn_sched_barrier(0);
            const float* vrow = &smem[VB + (ch * 64 + pix) * 13];
            const float* wr = wd + (size_t)gs * 4608 + (size_t)(r * 4 + ch) * 8;
            #pragma unroll
            for (int n = 0; n < 9; ++n) {
                float vv = vrow[n];
                const float* w8 = wr + n * 512;
                float4 wa = *(const float4*)w8;
                float4 wb = *(const float4*)(w8 + 4);
                accB[0] = fmaf(vv, wa.x, accB[0]);
                accB[1] = fmaf(vv, wa.y, accB[1]);
                accB[2] = fmaf(vv, wa.z, accB[2]);
                accB[3] = fmaf(vv, wa.w, accB[3]);
                accB[4] = fmaf(vv, wb.x, accB[4]);
                accB[5] = fmaf(vv, wb.y, accB[5]);
                accB[6] = fmaf(vv, wb.z, accB[6]);
                accB[7] = fmaf(vv, wb.w, accB[7]);
            }
        }
        if (r + 1 < 16) {
            int d = ((r + 1) & 1) * 1440;
            *(float4*)&smem[d + d0] = n0;
            if (tid < 104) *(float4*)&smem[d + d1] = n1;
        }
        __syncthreads();
    }

    // each group owns co slice gs*8..gs*8+7 -> direct write, no reduce
    #pragma unroll
    for (int c = 0; c < 8; ++c)
        out[((size_t)(b * 32 + gs * 8 + c) * HH + yh) * WW + xw] =
            fmaxf(accB[c], 0.f);
}

// =====================================================================
// fused_final: offset-conv(32->18) + deform + conv(32->4) + pixel shuffle
// ci-split (4 groups x 8 ch), acc[4] per thread, 4-way reduce.
// =====================================================================
__global__ __launch_bounds__(256) void fused_final(
        const float* __restrict__ feat,
        const float* __restrict__ wo, const float* __restrict__ bo,
        const float* __restrict__ wd, const float* __restrict__ bd,
        const u32* __restrict__ xu,
        float* __restrict__ outf, u32* __restrict__ outb) {
    __shared__ float smem[6784];   // win[0,2880) | red[2880,5568) | offb[5568,6784)
    constexpr int RED = 2880, OFB = 5568;
    bool bf = wave_flag(xu);
    int tid = threadIdx.x;
    int pix = tid & 63, g = tid >> 6;
    int gs = __builtin_amdgcn_readfirstlane(g);
    int bid = blockIdx.x;
    int hx = bid & 1, yh = (bid >> 1) & 127, b = bid >> 8;
    int xw = hx * 64 + pix, bx = hx * 64 - 4;
    float4 z4; z4.x = z4.y = z4.z = z4.w = 0.f;

    // ---- A staging: 216 slots = 4 ci-groups x 3 rows x 18 col4 ----
    int gA = tid / 54, remA = tid % 54;
    int rowA = remA / 18, c4A = remA % 18;
    int gyA = yh - 1 + rowA, gcA = bx + 4 * c4A;
    bool vA = (tid < 216) && ((unsigned)gyA < 128u) && ((unsigned)gcA < 128u);
    const float* spA = feat + ((size_t)(b * 32 + gA * 8) * HW + gyA * WW + gcA);
    int dA = 4 * tid;

    { float4 a0 = vA ? *(const float4*)spA : z4;
      if (tid < 216) *(float4*)&smem[dA] = a0; }
    __syncthreads();

    float acc[20];
    #pragma unroll
    for (int c = 0; c < 20; ++c) acc[c] = (g == 0 && c < 18) ? bo[c] : 0.f;

    #pragma unroll 1
    for (int r = 0; r < 8; ++r) {
        float4 n0 = z4;
        if (r + 1 < 8 && vA) n0 = *(const float4*)(spA + (size_t)(r + 1) * HW);
        const float* L = smem + (r & 1) * 864 + gs * 216;
        float v[9];
        #pragma unroll
        for (int ky = 0; ky < 3; ++ky) {
            const float* Lr = L + ky * 72 + pix + 3;
            v[ky * 3 + 0] = Lr[0];
            v[ky * 3 + 1] = Lr[1];
            v[ky * 3 + 2] = Lr[2];
        }
        const float* wr = wo + (size_t)(gs * 8 + r) * 180;
        #pragma unroll
        for (int k = 0; k < 9; ++k) {
            __builtin_amdgcn_sched_barrier(0);
            #pragma unroll
            for (int q = 0; q < 5; ++q) {
                float4 wv = *(const float4*)(wr + k * 20 + q * 4);
                acc[q * 4 + 0] = fmaf(v[k], wv.x, acc[q * 4 + 0]);
                acc[q * 4 + 1] = fmaf(v[k], wv.y, acc[q * 4 + 1]);
                acc[q * 4 + 2] = fmaf(v[k], wv.z, acc[q * 4 + 2]);
                acc[q * 4 + 3] = fmaf(v[k], wv.w, acc[q * 4 + 3]);
            }
        }
        if (r + 1 < 8 && tid < 216)
            *(float4*)&smem[((r + 1) & 1) * 864 + dA] = n0;
        __syncthreads();
    }
    if (g >= 2) {
        #pragma unroll
        for (int c = 0; c < 18; ++c) smem[RED + (g - 2) * 1344 + pix * 21 + c] = acc[c];
    }
    __syncthreads();
    if (g < 2) {
        #pragma unroll
        for (int c = 0; c < 18; ++c) acc[c] += smem[RED + g * 1344 + pix * 21 + c];
    }
    __syncthreads();
    if (g == 1) {
        #pragma unroll
        for (int c = 0; c < 18; ++c) smem[RED + pix * 21 + c] = acc[c];
    }
    __syncthreads();
    if (g == 0) {
        #pragma unroll
        for (int c = 0; c < 18; ++c)
            smem[OFB + pix * 19 + c] = acc[c] + smem[RED + pix * 21 + c];
    }
    __syncthreads();

    float wyA[9], wxA[9];
    int pk[9];
    #pragma unroll
    for (int n = 0; n < 9; ++n) {
        float py = smem[OFB + pix * 19 + n]     + (float)(n / 3 - 1 + yh);
        float px = smem[OFB + pix * 19 + 9 + n] + (float)(n % 3 - 1 + xw);
        py = fminf(fmaxf(py, 0.f), 127.f);
        px = fminf(fmaxf(px, 0.f), 127.f);
        float y0f = floorf(py), x0f = floorf(px);
        int y0 = (int)y0f, x0 = (int)x0f;
        int dy = (y0 < 127) ? 1 : 0;
        int dx = (x0 < 127) ? 1 : 0;
        wyA[n] = py - y0f;
        wxA[n] = px - x0f;
        int slot = y0 - yh + 2;
        int cix  = x0 - bx;
        bool inw = (slot >= 0) && (slot + dy <= 4) && (cix >= 0) && (cix + dx < 72);
        int a = slot * 72 + cix;
        pk[n] = (inw ? ((1 << 11) | a) : 0) | (dx << 9) | (dy << 10)
              | (x0 << 12) | (y0 << 19);
    }

    // ---- B staging: 360 slots = 4 ci-groups x 5 rows x 18 col4 ----
    int g0 = tid / 90, rem0 = tid % 90;
    int row0 = rem0 / 18, c40 = rem0 % 18;
    int gy0 = yh - 2 + row0, gc0 = bx + 4 * c40;
    bool v0 = ((unsigned)gy0 < 128u) && ((unsigned)gc0 < 128u);
    const float* sp0 = feat + ((size_t)(b * 32 + g0 * 8) * HW + gy0 * WW + gc0);
    int d0 = 4 * tid;
    int j1 = tid + 256;
    int g1 = j1 / 90, rem1 = j1 % 90;
    int row1 = rem1 / 18, c41 = rem1 % 18;
    int gy1 = yh - 2 + row1, gc1 = bx + 4 * c41;
    bool v1 = (tid < 104) && ((unsigned)gy1 < 128u) && ((unsigned)gc1 < 128u);
    const float* sp1 = feat + ((size_t)(b * 32 + g1 * 8) * HW + gy1 * WW + gc1);
    int d1 = 4 * j1;

    { float4 s0 = v0 ? *(const float4*)sp0 : z4;
      float4 s1 = v1 ? *(const float4*)sp1 : z4;
      *(float4*)&smem[d0] = s0;
      if (tid < 104) *(float4*)&smem[d1] = s1; }
    __syncthreads();

    float accB[4];
    #pragma unroll
    for (int c = 0; c < 4; ++c) accB[c] = (g == 0) ? bd[c] : 0.f;
    const float* fbg = feat + (size_t)(b * 32 + gs * 8) * HW;

    #pragma unroll 1
    for (int r = 0; r < 8; ++r) {
        float4 n0 = z4, n1 = z4;
        if (r + 1 < 8) {
            if (v0) n0 = *(const float4*)(sp0 + (size_t)(r + 1) * HW);
            if (v1) n1 = *(const float4*)(sp1 + (size_t)(r + 1) * HW);
        }
        const float* L = smem + (r & 1) * 1440 + gs * 360;
        #pragma unroll
        for (int n = 0; n < 9; ++n) {
            __builtin_amdgcn_sched_barrier(0);
            int p = pk[n];
            float wy = wyA[n], wx = wxA[n];
            int dxo = (p >> 9) & 1;
            float v;
            if (p & (1 << 11)) {
                int a = p & 511;
                int dyo = ((p >> 10) & 1) * 72;
                float p00 = L[a], p01 = L[a + dxo];
                float p10 = L[a + dyo], p11 = L[a + dyo + dxo];
                float top = fmaf(wx, p01 - p00, p00);
                float bot = fmaf(wx, p11 - p10, p10);
                v = fmaf(wy, bot - top, top);
            } else {
                int x0 = (p >> 12) & 127, y0 = (p >> 19) & 127;
                const float* fp = fbg + (size_t)r * HW + y0 * WW + x0;
                int dyo = ((p >> 10) & 1) * WW;
                float p00 = fp[0], p01 = fp[dxo];
                float p10 = fp[dyo], p11 = fp[dyo + dxo];
                float top = fmaf(wx, p01 - p00, p00);
                float bot = fmaf(wx, p11 - p10, p10);
                v = fmaf(wy, bot - top, top);
            }
            float4 wv = *(const float4*)(wd + (size_t)(n * 32 + gs * 8 + r) * 4);
            accB[0] = fmaf(v, wv.x, accB[0]);
            accB[1] = fmaf(v, wv.y, accB[1]);
            accB[2] = fmaf(v, wv.z, accB[2]);
            accB[3] = fmaf(v, wv.w, accB[3]);
        }
        if (r + 1 < 8) {
            int d = ((r + 1) & 1) * 1440;
            *(float4*)&smem[d + d0] = n0;
            if (tid < 104) *(float4*)&smem[d + d1] = n1;
        }
        __syncthreads();
    }

    if (g >= 2) {
        #pragma unroll
        for (int c = 0; c < 4; ++c) smem[RED + (g - 2) * 320 + pix * 5 + c] = accB[c];
    }
    __syncthreads();
    if (g < 2) {
        #pragma unroll
        for (int c = 0; c < 4; ++c) accB[c] += smem[RED + g * 320 + pix * 5 + c];
    }
    __syncthreads();
    if (g == 1) {
        #pragma unroll
        for (int c = 0; c < 4; ++c) smem[RED + pix * 5 + c] = accB[c];
    }
    __syncthreads();
    if (g == 0) {
        #pragma unroll
        for (int c = 0; c < 4; ++c) accB[c] += smem[RED + pix * 5 + c];
        if (bf) {
            u32 p0 = ((u32)f2bf(accB[1]) << 16) | (u32)f2bf(accB[0]);
            u32 p1 = ((u32)f2bf(accB[3]) << 16) | (u32)f2bf(accB[2]);
            outb[(size_t)(b * 256 + 2 * yh) * 128 + xw]     = p0;
            outb[(size_t)(b * 256 + 2 * yh + 1) * 128 + xw] = p1;
        } else {
            float* o = outf;
            size_t r0 = (size_t)(b * 256 + 2 * yh) * 256 + 2 * xw;
            o[r0]       = accB[0];
            o[r0 + 1]   = accB[1];
            o[r0 + 256] = accB[2];
            o[r0 + 257] = accB[3];
        }
    }
}

extern "C" void kernel_launch(void* const* d_in, const int* in_sizes, int n_in,
                              void* d_out, int out_size, void* d_ws, size_t ws_size,
                              hipStream_t stream) {
    float* ws = (float*)d_ws;
    const u32* xu = (const u32*)d_in[0];
    prep_weights<<<72, 256, 0, stream>>>(xu, d_in[3], d_in[4], d_in[5], d_in[6],
                                         d_in[7], d_in[8], d_in[9], d_in[10], ws);
    conv1_kernel<<<4096, 256, 0, stream>>>(xu, d_in[0], d_in[1], d_in[2], ws + O_H1);
    fused_mid<<<1024, 256, 0, stream>>>(
        ws + O_H1, ws + O_WO2T, ws + O_BO2, ws + O_W2T, ws + O_B2, ws + O_H2);
    fused_final<<<1024, 256, 0, stream>>>(
        ws + O_H2, ws + O_WO3T, ws + O_BO3, ws + O_W3T, ws + O_B3,
        xu, (float*)d_out, (u32*)d_out);
}

// Round 6
// 284.774 us; speedup vs baseline: 1.5899x; 1.2915x over previous
//
#include <hip/hip_runtime.h>

#define HH 128
#define WW 128
#define HW (HH*WW)

// ---- ws layout (float offsets) ----
#define O_H1   0u         // (4,64,128,128) f32
#define O_H2   4194304u   // (4,32,128,128) f32
#define O_WO2T 6291456u   // [ci64][k9][co20] = 11520
#define O_W2T  6302976u   // [ci64][n9][co32] = 18432
#define O_WO3T 6321408u   // [ci32][k9][co20] = 5760
#define O_W3T  6327168u   // [n9][ci32][co4]  = 1152
#define O_BO2  6328320u
#define O_B2   6328352u
#define O_BO3  6328384u
#define O_B3   6328416u

typedef unsigned short u16;
typedef unsigned int   u32;

__device__ __forceinline__ float bf2f(u16 h) {
    return __uint_as_float(((u32)h) << 16);
}
__device__ __forceinline__ u16 f2bf(float f) {   // round-to-nearest-even
    u32 u = __float_as_uint(f);
    return (u16)((u + 0x7FFFu + ((u >> 16) & 1u)) >> 16);
}
__device__ __forceinline__ float ldm(const void* p, int i, bool bf) {
    return bf ? bf2f(((const u16*)p)[i]) : ((const float*)p)[i];
}
// wave-uniform dtype flag from first 64 words of x (see round-2 notes)
__device__ __forceinline__ bool wave_flag(const u32* xu) {
    u32 w = xu[threadIdx.x & 63];
    u32 lo = w & 0xFFFFu;
    u32 e = (lo >> 7) & 0xFFu;
    bool ok = (lo != 0u) && (e >= 100u) && (e <= 140u);
    return __popcll(__ballot(ok)) > 32;
}

// ---- weights -> f32, transposed/padded ----
__global__ __launch_bounds__(256) void prep_weights(
        const u32* xu,
        const void* wo2, const void* bo2, const void* w2, const void* b2,
        const void* wo3, const void* bo3, const void* w3, const void* b3,
        float* ws) {
    bool bf = wave_flag(xu);
    int i = blockIdx.x * 256 + threadIdx.x;
    if (i < 11520) {                     // wo2t [ci][k][co20]
        int co = i % 20, k = (i / 20) % 9, ci = i / 180;
        ws[O_WO2T + i] = (co < 18) ? ldm(wo2, (co * 64 + ci) * 9 + k, bf) : 0.f;
    }
    if (i < 18432) {                     // w2t [ci64][n9][co32]
        int co = i & 31, n = (i >> 5) % 9, ci = i / 288;
        ws[O_W2T + i] = ldm(w2, (co * 64 + ci) * 9 + n, bf);
    }
    if (i < 5760) {                      // wo3t [ci][k][co20]
        int co = i % 20, k = (i / 20) % 9, ci = i / 180;
        ws[O_WO3T + i] = (co < 18) ? ldm(wo3, (co * 32 + ci) * 9 + k, bf) : 0.f;
    }
    if (i < 1152) {                      // w3t [n][ci][co4]
        int co = i & 3, ci = (i >> 2) & 31, n = i / 128;
        ws[O_W3T + i] = ldm(w3, (co * 32 + ci) * 9 + n, bf);
    }
    if (i < 18) ws[O_BO2 + i] = ldm(bo2, i, bf);
    if (i < 32) ws[O_B2 + i]  = ldm(b2, i, bf);
    if (i < 18) ws[O_BO3 + i] = ldm(bo3, i, bf);
    if (i < 4)  ws[O_B3 + i]  = ldm(b3, i, bf);
}

// conv1: x (B,1,H,W) -> h1 (B,64,H,W) f32, relu, pad 1. 4 co per thread.
__global__ __launch_bounds__(256) void conv1_kernel(
        const u32* xu, const void* x, const void* w, const void* bias,
        float* __restrict__ out) {
    bool bf = wave_flag(xu);
    int idx = blockIdx.x * 256 + threadIdx.x;
    int xw = idx & 127; int t = idx >> 7;
    int yh = t & 127;   t >>= 7;
    int cg = t & 15;    int b = t >> 4;
    float xv[9];
    #pragma unroll
    for (int ky = 0; ky < 3; ++ky) {
        int yy = yh + ky - 1;
        #pragma unroll
        for (int kx = 0; kx < 3; ++kx) {
            int xx = xw + kx - 1;
            xv[ky * 3 + kx] =
                ((unsigned)yy < 128u && (unsigned)xx < 128u)
                    ? ldm(x, b * HW + yy * WW + xx, bf) : 0.f;
        }
    }
    #pragma unroll
    for (int j = 0; j < 4; ++j) {
        int co = cg * 4 + j;
        float acc = ldm(bias, co, bf);
        #pragma unroll
        for (int k = 0; k < 9; ++k)
            acc = fmaf(ldm(w, co * 9 + k, bf), xv[k], acc);
        out[((size_t)(b * 64 + co) * HH + yh) * WW + xw] = fmaxf(acc, 0.f);
    }
}

// =====================================================================
// fused_mid: offset-conv(64->18) + deform + stride-3 conv(64->32) + relu
// Block = 64-px half-row, 4 waves. Weights staged per-round into LDS.
// LDS map (f32): A-phase: winA dbuf [0,1728) wA dbuf [1728,3168)
//                         redA [3168,5856)
//                B-phase: winB dbuf [0,2880) wB dbuf [2880,5184)
//                         vbuf [5184,7488)
//                shared:  offb [7488,8704)
// =====================================================================
#define M_WA   1728
#define M_REDA 3168
#define M_WB   2880
#define M_VB   5184
#define M_OFB  7488

__global__ __launch_bounds__(256) void fused_mid(
        const float* __restrict__ feat,
        const float* __restrict__ wo, const float* __restrict__ bo,
        const float* __restrict__ wd, const float* __restrict__ bd,
        float* __restrict__ out) {
    __shared__ float smem[8704];
    int tid = threadIdx.x;
    int pix = tid & 63, g = tid >> 6;
    int gs = __builtin_amdgcn_readfirstlane(g);
    int bid = blockIdx.x;
    int hx = bid & 1, yh = (bid >> 1) & 127, b = bid >> 8;
    int xw = hx * 64 + pix, bx = hx * 64 - 4;
    float4 z4; z4.x = z4.y = z4.z = z4.w = 0.f;

    // ---- A window staging: 216 slots = 4 g x 3 rows x 18 col4 ----
    int gA = tid / 54, remA = tid % 54;
    int rowA = remA / 18, c4A = remA % 18;
    int gyA = yh - 1 + rowA, gcA = bx + 4 * c4A;
    bool vA = (tid < 216) && ((unsigned)gyA < 128u) && ((unsigned)gcA < 128u);
    const float* spA = feat + ((size_t)(b * 64 + gA * 16) * HW + gyA * WW + gcA);
    int dA = 4 * tid;

    // ---- A weight staging: 180 f4 slots = 4 g x 45 ----
    int wag = tid / 45, wai = tid % 45;
    bool vWA = tid < 180;
    const float* wsrcA = wo + (size_t)wag * 2880 + wai * 4;   // + r*180
    int dWA = wag * 180 + wai * 4;

    { float4 a0 = vA ? *(const float4*)spA : z4;
      if (tid < 216) *(float4*)&smem[dA] = a0;
      if (vWA) *(float4*)&smem[M_WA + dWA] = *(const float4*)wsrcA; }
    __syncthreads();

    // ================= phase A: offset conv (ci-split) =================
    float acc[20];
    #pragma unroll
    for (int c = 0; c < 20; ++c) acc[c] = (g == 0 && c < 18) ? bo[c] : 0.f;

    #pragma unroll 1
    for (int r = 0; r < 16; ++r) {
        float4 n0 = z4, nw = z4;
        if (r + 1 < 16) {
            if (vA)  n0 = *(const float4*)(spA + (size_t)(r + 1) * HW);
            if (vWA) nw = *(const float4*)(wsrcA + (size_t)(r + 1) * 180);
        }
        const float* L = smem + (r & 1) * 864 + gs * 216;
        float v[9];
        #pragma unroll
        for (int ky = 0; ky < 3; ++ky) {
            const float* Lr = L + ky * 72 + pix + 3;
            v[ky * 3 + 0] = Lr[0];
            v[ky * 3 + 1] = Lr[1];
            v[ky * 3 + 2] = Lr[2];
        }
        const float* wr = smem + M_WA + (r & 1) * 720 + gs * 180;
        #pragma unroll
        for (int k = 0; k < 9; ++k) {
            __builtin_amdgcn_sched_barrier(0);
            #pragma unroll
            for (int q = 0; q < 5; ++q) {
                float4 wv = *(const float4*)(wr + k * 20 + q * 4);
                acc[q * 4 + 0] = fmaf(v[k], wv.x, acc[q * 4 + 0]);
                acc[q * 4 + 1] = fmaf(v[k], wv.y, acc[q * 4 + 1]);
                acc[q * 4 + 2] = fmaf(v[k], wv.z, acc[q * 4 + 2]);
                acc[q * 4 + 3] = fmaf(v[k], wv.w, acc[q * 4 + 3]);
            }
        }
        if (r + 1 < 16) {
            if (tid < 216) *(float4*)&smem[((r + 1) & 1) * 864 + dA] = n0;
            if (vWA) *(float4*)&smem[M_WA + ((r + 1) & 1) * 720 + dWA] = nw;
        }
        __syncthreads();
    }
    // 4-way reduce -> offb
    if (g >= 2) {
        #pragma unroll
        for (int c = 0; c < 18; ++c)
            smem[M_REDA + (g - 2) * 1344 + pix * 21 + c] = acc[c];
    }
    __syncthreads();
    if (g < 2) {
        #pragma unroll
        for (int c = 0; c < 18; ++c)
            acc[c] += smem[M_REDA + g * 1344 + pix * 21 + c];
    }
    __syncthreads();
    if (g == 1) {
        #pragma unroll
        for (int c = 0; c < 18; ++c) smem[M_REDA + pix * 21 + c] = acc[c];
    }
    __syncthreads();
    if (g == 0) {
        #pragma unroll
        for (int c = 0; c < 18; ++c)
            smem[M_OFB + pix * 19 + c] = acc[c] + smem[M_REDA + pix * 21 + c];
    }
    __syncthreads();

    // ================= geometry =================
    float wyA[9], wxA[9];
    int pk[9];
    #pragma unroll
    for (int n = 0; n < 9; ++n) {
        float py = smem[M_OFB + pix * 19 + n]     + (float)(n / 3 - 1 + yh);
        float px = smem[M_OFB + pix * 19 + 9 + n] + (float)(n % 3 - 1 + xw);
        py = fminf(fmaxf(py, 0.f), 127.f);
        px = fminf(fmaxf(px, 0.f), 127.f);
        float y0f = floorf(py), x0f = floorf(px);
        int y0 = (int)y0f, x0 = (int)x0f;
        int dy = (y0 < 127) ? 1 : 0;
        int dx = (x0 < 127) ? 1 : 0;
        wyA[n] = py - y0f;
        wxA[n] = px - x0f;
        int slot = y0 - yh + 2;
        int cix  = x0 - bx;
        bool inw = (slot >= 0) && (slot + dy <= 4) && (cix >= 0) && (cix + dx < 72);
        int a = slot * 72 + cix;
        pk[n] = (inw ? ((1 << 11) | a) : 0) | (dx << 9) | (dy << 10)
              | (x0 << 12) | (y0 << 19);
    }

    // ---- B window staging: 360 slots = 4 round-ch x 5 rows x 18 col4 ----
    int ch0 = tid / 90, rem0 = tid % 90;
    int row0 = rem0 / 18, c40 = rem0 % 18;
    int gy0 = yh - 2 + row0, gc0 = bx + 4 * c40;
    bool v0 = ((unsigned)gy0 < 128u) && ((unsigned)gc0 < 128u);
    const float* sp0 = feat + ((size_t)(b * 64 + ch0) * HW + gy0 * WW + gc0);
    int d0 = 4 * tid;
    int j1 = tid + 256;
    int ch1 = j1 / 90, rem1 = j1 % 90;
    int row1 = rem1 / 18, c41 = rem1 % 18;
    int gy1 = yh - 2 + row1, gc1 = bx + 4 * c41;
    bool v1 = (tid < 104) && ((unsigned)gy1 < 128u) && ((unsigned)gc1 < 128u);
    const float* sp1 = feat + ((size_t)(b * 64 + ch1) * HW + gy1 * WW + gc1);
    int d1 = 4 * j1;

    // ---- B weight staging: 288 f4 slots (tid + tid<32 second) ----
    const float* wsrcB0 = wd + (size_t)tid * 4;            // + r*1152
    const float* wsrcB1 = wd + (size_t)(256 + tid) * 4;
    int dWB0 = tid * 4, dWB1 = (256 + tid) * 4;

    { float4 s0 = v0 ? *(const float4*)sp0 : z4;
      float4 s1 = v1 ? *(const float4*)sp1 : z4;
      *(float4*)&smem[d0] = s0;
      if (tid < 104) *(float4*)&smem[d1] = s1;
      *(float4*)&smem[M_WB + dWB0] = *(const float4*)wsrcB0;
      if (tid < 32) *(float4*)&smem[M_WB + dWB1] = *(const float4*)wsrcB1; }
    __syncthreads();

    // ================= phase B: deform + conv (co-split) =================
    float accB[8];
    #pragma unroll
    for (int c = 0; c < 8; ++c) accB[c] = bd[gs * 8 + c];

    #pragma unroll 1
    for (int r = 0; r < 16; ++r) {
        float4 n0 = z4, n1 = z4, nb0 = z4, nb1 = z4;
        if (r + 1 < 16) {
            if (v0) n0 = *(const float4*)(sp0 + (size_t)(r + 1) * 4 * HW);
            if (v1) n1 = *(const float4*)(sp1 + (size_t)(r + 1) * 4 * HW);
            nb0 = *(const float4*)(wsrcB0 + (size_t)(r + 1) * 1152);
            if (tid < 32) nb1 = *(const float4*)(wsrcB1 + (size_t)(r + 1) * 1152);
        }
        // B1: sample my channel (c = r*4+gs) at all 9 taps -> vbuf
        {
            const float* Lg = smem + (r & 1) * 1440 + gs * 360;
            const float* fbg = feat + (size_t)(b * 64 + r * 4 + gs) * HW;
            #pragma unroll
            for (int n = 0; n < 9; ++n) {
                __builtin_amdgcn_sched_barrier(0);
                int p = pk[n];
                float wy = wyA[n], wx = wxA[n];
                int dxo = (p >> 9) & 1;
                float val;
                if (p & (1 << 11)) {
                    int a = p & 511;
                    int dyo = ((p >> 10) & 1) * 72;
                    float p00 = Lg[a], p01 = Lg[a + dxo];
                    float p10 = Lg[a + dyo], p11 = Lg[a + dyo + dxo];
                    float top = fmaf(wx, p01 - p00, p00);
                    float bot = fmaf(wx, p11 - p10, p10);
                    val = fmaf(wy, bot - top, top);
                } else {       // out-of-window fallback (general offsets)
                    int x0 = (p >> 12) & 127, y0 = (p >> 19) & 127;
                    const float* fp = fbg + y0 * WW + x0;
                    int dyo = ((p >> 10) & 1) * WW;
                    float p00 = fp[0], p01 = fp[dxo];
                    float p10 = fp[dyo], p11 = fp[dyo + dxo];
                    float top = fmaf(wx, p01 - p00, p00);
                    float bot = fmaf(wx, p11 - p10, p10);
                    val = fmaf(wy, bot - top, top);
                }
                smem[M_VB + (gs * 64 + pix) * 9 + n] = val;
            }
        }
        __syncthreads();
        // B2: each group FMAs its 8-co slice over the 4 round-channels
        #pragma unroll
        for (int ch = 0; ch < 4; ++ch) {
            __builtin_amdgcn_sched_barrier(0);
            const float* vrow = &smem[M_VB + (ch * 64 + pix) * 9];
            const float* wr = smem + M_WB + (r & 1) * 1152 + ch * 288 + gs * 8;
            #pragma unroll
            for (int n = 0; n < 9; ++n) {
                float vv = vrow[n];
                const float* w8 = wr + n * 32;
                float4 wa = *(const float4*)w8;
                float4 wb = *(const float4*)(w8 + 4);
                accB[0] = fmaf(vv, wa.x, accB[0]);
                accB[1] = fmaf(vv, wa.y, accB[1]);
                accB[2] = fmaf(vv, wa.z, accB[2]);
                accB[3] = fmaf(vv, wa.w, accB[3]);
                accB[4] = fmaf(vv, wb.x, accB[4]);
                accB[5] = fmaf(vv, wb.y, accB[5]);
                accB[6] = fmaf(vv, wb.z, accB[6]);
                accB[7] = fmaf(vv, wb.w, accB[7]);
            }
        }
        if (r + 1 < 16) {
            int d = ((r + 1) & 1) * 1440;
            *(float4*)&smem[d + d0] = n0;
            if (tid < 104) *(float4*)&smem[d + d1] = n1;
            int dw = M_WB + ((r + 1) & 1) * 1152;
            *(float4*)&smem[dw + dWB0] = nb0;
            if (tid < 32) *(float4*)&smem[dw + dWB1] = nb1;
        }
        __syncthreads();
    }

    // each group owns co slice gs*8..gs*8+7 -> direct write, no reduce
    #pragma unroll
    for (int c = 0; c < 8; ++c)
        out[((size_t)(b * 32 + gs * 8 + c) * HH + yh) * WW + xw] =
            fmaxf(accB[c], 0.f);
}

// =====================================================================
// fused_final: offset-conv(32->18) + deform + conv(32->4) + pixel shuffle
// ci-split both phases. Weights in LDS (A per-round dbuf; B staged once).
// LDS map (f32): winA dbuf [0,1728) wA dbuf [1728,3168) wB [3168,4320)
//                red [4320,7008) offb [7008,8224); winB dbuf [0,2880)
// =====================================================================
#define F_WA   1728
#define F_WB   3168
#define F_RED  4320
#define F_OFB  7008

__global__ __launch_bounds__(256) void fused_final(
        const float* __restrict__ feat,
        const float* __restrict__ wo, const float* __restrict__ bo,
        const float* __restrict__ wd, const float* __restrict__ bd,
        const u32* __restrict__ xu,
        float* __restrict__ outf, u32* __restrict__ outb) {
    __shared__ float smem[8224];
    bool bf = wave_flag(xu);
    int tid = threadIdx.x;
    int pix = tid & 63, g = tid >> 6;
    int gs = __builtin_amdgcn_readfirstlane(g);
    int bid = blockIdx.x;
    int hx = bid & 1, yh = (bid >> 1) & 127, b = bid >> 8;
    int xw = hx * 64 + pix, bx = hx * 64 - 4;
    float4 z4; z4.x = z4.y = z4.z = z4.w = 0.f;

    // ---- A window staging ----
    int gA = tid / 54, remA = tid % 54;
    int rowA = remA / 18, c4A = remA % 18;
    int gyA = yh - 1 + rowA, gcA = bx + 4 * c4A;
    bool vA = (tid < 216) && ((unsigned)gyA < 128u) && ((unsigned)gcA < 128u);
    const float* spA = feat + ((size_t)(b * 32 + gA * 8) * HW + gyA * WW + gcA);
    int dA = 4 * tid;
    // ---- A weight staging: 180 f4 ----
    int wag = tid / 45, wai = tid % 45;
    bool vWA = tid < 180;
    const float* wsrcA = wo + (size_t)wag * 1440 + wai * 4;   // + r*180
    int dWA = wag * 180 + wai * 4;
    // ---- B weights staged once: 288 f4 ----
    { float4 a0 = vA ? *(const float4*)spA : z4;
      if (tid < 216) *(float4*)&smem[dA] = a0;
      if (vWA) *(float4*)&smem[F_WA + dWA] = *(const float4*)wsrcA;
      *(float4*)&smem[F_WB + tid * 4] = *(const float4*)(wd + (size_t)tid * 4);
      if (tid < 32)
          *(float4*)&smem[F_WB + (256 + tid) * 4] =
              *(const float4*)(wd + (size_t)(256 + tid) * 4); }
    __syncthreads();

    float acc[20];
    #pragma unroll
    for (int c = 0; c < 20; ++c) acc[c] = (g == 0 && c < 18) ? bo[c] : 0.f;

    #pragma unroll 1
    for (int r = 0; r < 8; ++r) {
        float4 n0 = z4, nw = z4;
        if (r + 1 < 8) {
            if (vA)  n0 = *(const float4*)(spA + (size_t)(r + 1) * HW);
            if (vWA) nw = *(const float4*)(wsrcA + (size_t)(r + 1) * 180);
        }
        const float* L = smem + (r & 1) * 864 + gs * 216;
        float v[9];
        #pragma unroll
        for (int ky = 0; ky < 3; ++ky) {
            const float* Lr = L + ky * 72 + pix + 3;
            v[ky * 3 + 0] = Lr[0];
            v[ky * 3 + 1] = Lr[1];
            v[ky * 3 + 2] = Lr[2];
        }
        const float* wr = smem + F_WA + (r & 1) * 720 + gs * 180;
        #pragma unroll
        for (int k = 0; k < 9; ++k) {
            __builtin_amdgcn_sched_barrier(0);
            #pragma unroll
            for (int q = 0; q < 5; ++q) {
                float4 wv = *(const float4*)(wr + k * 20 + q * 4);
                acc[q * 4 + 0] = fmaf(v[k], wv.x, acc[q * 4 + 0]);
                acc[q * 4 + 1] = fmaf(v[k], wv.y, acc[q * 4 + 1]);
                acc[q * 4 + 2] = fmaf(v[k], wv.z, acc[q * 4 + 2]);
                acc[q * 4 + 3] = fmaf(v[k], wv.w, acc[q * 4 + 3]);
            }
        }
        if (r + 1 < 8) {
            if (tid < 216) *(float4*)&smem[((r + 1) & 1) * 864 + dA] = n0;
            if (vWA) *(float4*)&smem[F_WA + ((r + 1) & 1) * 720 + dWA] = nw;
        }
        __syncthreads();
    }
    if (g >= 2) {
        #pragma unroll
        for (int c = 0; c < 18; ++c)
            smem[F_RED + (g - 2) * 1344 + pix * 21 + c] = acc[c];
    }
    __syncthreads();
    if (g < 2) {
        #pragma unroll
        for (int c = 0; c < 18; ++c)
            acc[c] += smem[F_RED + g * 1344 + pix * 21 + c];
    }
    __syncthreads();
    if (g == 1) {
        #pragma unroll
        for (int c = 0; c < 18; ++c) smem[F_RED + pix * 21 + c] = acc[c];
    }
    __syncthreads();
    if (g == 0) {
        #pragma unroll
        for (int c = 0; c < 18; ++c)
            smem[F_OFB + pix * 19 + c] = acc[c] + smem[F_RED + pix * 21 + c];
    }
    __syncthreads();

    float wyA[9], wxA[9];
    int pk[9];
    #pragma unroll
    for (int n = 0; n < 9; ++n) {
        float py = smem[F_OFB + pix * 19 + n]     + (float)(n / 3 - 1 + yh);
        float px = smem[F_OFB + pix * 19 + 9 + n] + (float)(n % 3 - 1 + xw);
        py = fminf(fmaxf(py, 0.f), 127.f);
        px = fminf(fmaxf(px, 0.f), 127.f);
        float y0f = floorf(py), x0f = floorf(px);
        int y0 = (int)y0f, x0 = (int)x0f;
        int dy = (y0 < 127) ? 1 : 0;
        int dx = (x0 < 127) ? 1 : 0;
        wyA[n] = py - y0f;
        wxA[n] = px - x0f;
        int slot = y0 - yh + 2;
        int cix  = x0 - bx;
        bool inw = (slot >= 0) && (slot + dy <= 4) && (cix >= 0) && (cix + dx < 72);
        int a = slot * 72 + cix;
        pk[n] = (inw ? ((1 << 11) | a) : 0) | (dx << 9) | (dy << 10)
              | (x0 << 12) | (y0 << 19);
    }

    // ---- B window staging: 360 slots = 4 ci-groups x 5 rows x 18 col4 ----
    int g0 = tid / 90, rem0 = tid % 90;
    int row0 = rem0 / 18, c40 = rem0 % 18;
    int gy0 = yh - 2 + row0, gc0 = bx + 4 * c40;
    bool v0 = ((unsigned)gy0 < 128u) && ((unsigned)gc0 < 128u);
    const float* sp0 = feat + ((size_t)(b * 32 + g0 * 8) * HW + gy0 * WW + gc0);
    int d0 = 4 * tid;
    int j1 = tid + 256;
    int g1 = j1 / 90, rem1 = j1 % 90;
    int row1 = rem1 / 18, c41 = rem1 % 18;
    int gy1 = yh - 2 + row1, gc1 = bx + 4 * c41;
    bool v1 = (tid < 104) && ((unsigned)gy1 < 128u) && ((unsigned)gc1 < 128u);
    const float* sp1 = feat + ((size_t)(b * 32 + g1 * 8) * HW + gy1 * WW + gc1);
    int d1 = 4 * j1;

    { float4 s0 = v0 ? *(const float4*)sp0 : z4;
      float4 s1 = v1 ? *(const float4*)sp1 : z4;
      *(float4*)&smem[d0] = s0;
      if (tid < 104) *(float4*)&smem[d1] = s1; }
    __syncthreads();

    float accB[4];
    #pragma unroll
    for (int c = 0; c < 4; ++c) accB[c] = (g == 0) ? bd[c] : 0.f;
    const float* fbg = feat + (size_t)(b * 32 + gs * 8) * HW;

    #pragma unroll 1
    for (int r = 0; r < 8; ++r) {
        float4 n0 = z4, n1 = z4;
        if (r + 1 < 8) {
            if (v0) n0 = *(const float4*)(sp0 + (size_t)(r + 1) * HW);
            if (v1) n1 = *(const float4*)(sp1 + (size_t)(r + 1) * HW);
        }
        const float* L = smem + (r & 1) * 1440 + gs * 360;
        #pragma unroll
        for (int n = 0; n < 9; ++n) {
            __builtin_amdgcn_sched_barrier(0);
            int p = pk[n];
            float wy = wyA[n], wx = wxA[n];
            int dxo = (p >> 9) & 1;
            float v;
            if (p & (1 << 11)) {
                int a = p & 511;
                int dyo = ((p >> 10) & 1) * 72;
                float p00 = L[a], p01 = L[a + dxo];
                float p10 = L[a + dyo], p11 = L[a + dyo + dxo];
                float top = fmaf(wx, p01 - p00, p00);
                float bot = fmaf(wx, p11 - p10, p10);
                v = fmaf(wy, bot - top, top);
            } else {
                int x0 = (p >> 12) & 127, y0 = (p >> 19) & 127;
                const float* fp = fbg + (size_t)r * HW + y0 * WW + x0;
                int dyo = ((p >> 10) & 1) * WW;
                float p00 = fp[0], p01 = fp[dxo];
                float p10 = fp[dyo], p11 = fp[dyo + dxo];
                float top = fmaf(wx, p01 - p00, p00);
                float bot = fmaf(wx, p11 - p10, p10);
                v = fmaf(wy, bot - top, top);
            }
            float4 wv = *(const float4*)(smem + F_WB + (n * 32 + gs * 8 + r) * 4);
            accB[0] = fmaf(v, wv.x, accB[0]);
            accB[1] = fmaf(v, wv.y, accB[1]);
            accB[2] = fmaf(v, wv.z, accB[2]);
            accB[3] = fmaf(v, wv.w, accB[3]);
        }
        if (r + 1 < 8) {
            int d = ((r + 1) & 1) * 1440;
            *(float4*)&smem[d + d0] = n0;
            if (tid < 104) *(float4*)&smem[d + d1] = n1;
        }
        __syncthreads();
    }

    if (g >= 2) {
        #pragma unroll
        for (int c = 0; c < 4; ++c)
            smem[F_RED + (g - 2) * 320 + pix * 5 + c] = accB[c];
    }
    __syncthreads();
    if (g < 2) {
        #pragma unroll
        for (int c = 0; c < 4; ++c) accB[c] += smem[F_RED + g * 320 + pix * 5 + c];
    }
    __syncthreads();
    if (g == 1) {
        #pragma unroll
        for (int c = 0; c < 4; ++c) smem[F_RED + pix * 5 + c] = accB[c];
    }
    __syncthreads();
    if (g == 0) {
        #pragma unroll
        for (int c = 0; c < 4; ++c) accB[c] += smem[F_RED + pix * 5 + c];
        if (bf) {
            u32 p0 = ((u32)f2bf(accB[1]) << 16) | (u32)f2bf(accB[0]);
            u32 p1 = ((u32)f2bf(accB[3]) << 16) | (u32)f2bf(accB[2]);
            outb[(size_t)(b * 256 + 2 * yh) * 128 + xw]     = p0;
            outb[(size_t)(b * 256 + 2 * yh + 1) * 128 + xw] = p1;
        } else {
            float* o = outf;
            size_t r0 = (size_t)(b * 256 + 2 * yh) * 256 + 2 * xw;
            o[r0]       = accB[0];
            o[r0 + 1]   = accB[1];
            o[r0 + 256] = accB[2];
            o[r0 + 257] = accB[3];
        }
    }
}

extern "C" void kernel_launch(void* const* d_in, const int* in_sizes, int n_in,
                              void* d_out, int out_size, void* d_ws, size_t ws_size,
                              hipStream_t stream) {
    float* ws = (float*)d_ws;
    const u32* xu = (const u32*)d_in[0];
    prep_weights<<<72, 256, 0, stream>>>(xu, d_in[3], d_in[4], d_in[5], d_in[6],
                                         d_in[7], d_in[8], d_in[9], d_in[10], ws);
    conv1_kernel<<<4096, 256, 0, stream>>>(xu, d_in[0], d_in[1], d_in[2], ws + O_H1);
    fused_mid<<<1024, 256, 0, stream>>>(
        ws + O_H1, ws + O_WO2T, ws + O_BO2, ws + O_W2T, ws + O_B2, ws + O_H2);
    fused_final<<<1024, 256, 0, stream>>>(
        ws + O_H2, ws + O_WO3T, ws + O_BO3, ws + O_W3T, ws + O_B3,
        xu, (float*)d_out, (u32*)d_out);
}

// Round 7
// 112.648 us; speedup vs baseline: 4.0194x; 2.5280x over previous
//
#include <hip/hip_runtime.h>

#define HH 128
#define WW 128
#define HW (HH*WW)

// ---- ws layout (f32 indices) ----
#define O_H1   0u         // f32 h1 (4,64,128,128)
#define O_H2   4194304u   // u16 h2 (4,32,128,128) = 1048576 f32 slots
#define O_BTA2 5242880u   // u16[32*576]  Bt offconv2 [co][kk*64+ci]
#define O_BTB2 5252096u   // u16[32*576]  Bt deform2  [co][n*64+ci]
#define O_BTA3 5261312u   // u16[32*288]  Bt offconv3 [co][kk*32+ci]
#define O_BTB3 5265920u   // u16[16*288]  Bt deform3  [co][n*32+ci]
#define O_BO2  5268224u
#define O_B2   5268242u
#define O_BO3  5268274u
#define O_B3   5268292u

typedef unsigned short u16;
typedef unsigned int   u32;
typedef short  short8 __attribute__((ext_vector_type(8)));
typedef float  f32x4  __attribute__((ext_vector_type(4)));

__device__ __forceinline__ float bf2f(u16 h) {
    return __uint_as_float(((u32)h) << 16);
}
__device__ __forceinline__ u16 f2bf(float f) {   // round-to-nearest-even
    u32 u = __float_as_uint(f);
    return (u16)((u + 0x7FFFu + ((u >> 16) & 1u)) >> 16);
}
__device__ __forceinline__ float ldm(const void* p, int i, bool bf) {
    return bf ? bf2f(((const u16*)p)[i]) : ((const float*)p)[i];
}
// wave-uniform dtype flag from first 64 words of x (see round-2 notes)
__device__ __forceinline__ bool wave_flag(const u32* xu) {
    u32 w = xu[threadIdx.x & 63];
    u32 lo = w & 0xFFFFu;
    u32 e = (lo >> 7) & 0xFFu;
    bool ok = (lo != 0u) && (e >= 100u) && (e <= 140u);
    return __popcll(__ballot(ok)) > 32;
}

// ---- weights -> bf16, MFMA-transposed Bt[col][K] ----
__global__ __launch_bounds__(256) void prep_weights(
        const u32* xu,
        const void* wo2, const void* bo2, const void* w2, const void* b2,
        const void* wo3, const void* bo3, const void* w3, const void* b3,
        float* ws) {
    bool bf = wave_flag(xu);
    int i = blockIdx.x * 256 + threadIdx.x;
    u16* btA2 = (u16*)(ws + O_BTA2);
    u16* btB2 = (u16*)(ws + O_BTB2);
    u16* btA3 = (u16*)(ws + O_BTA3);
    u16* btB3 = (u16*)(ws + O_BTB3);
    if (i < 18432) {                   // K = kk*64+ci / n*64+ci
        int co = i / 576, K = i % 576, k9 = K >> 6, ci = K & 63;
        btA2[i] = f2bf(co < 18 ? ldm(wo2, (co * 64 + ci) * 9 + k9, bf) : 0.f);
        btB2[i] = f2bf(ldm(w2, (co * 64 + ci) * 9 + k9, bf));
    }
    if (i < 9216) {
        int co = i / 288, K = i % 288, k9 = K >> 5, ci = K & 31;
        btA3[i] = f2bf(co < 18 ? ldm(wo3, (co * 32 + ci) * 9 + k9, bf) : 0.f);
    }
    if (i < 4608) {
        int co = i / 288, K = i % 288, k9 = K >> 5, ci = K & 31;
        btB3[i] = f2bf(co < 4 ? ldm(w3, (co * 32 + ci) * 9 + k9, bf) : 0.f);
    }
    if (i < 18) ws[O_BO2 + i] = ldm(bo2, i, bf);
    if (i < 32) ws[O_B2 + i]  = ldm(b2, i, bf);
    if (i < 18) ws[O_BO3 + i] = ldm(bo3, i, bf);
    if (i < 4)  ws[O_B3 + i]  = ldm(b3, i, bf);
}

// conv1: x (B,1,H,W) -> h1 (B,64,H,W) f32, relu, pad 1. 4 co per thread.
__global__ __launch_bounds__(256) void conv1_kernel(
        const u32* xu, const void* x, const void* w, const void* bias,
        float* __restrict__ out) {
    bool bf = wave_flag(xu);
    int idx = blockIdx.x * 256 + threadIdx.x;
    int xw = idx & 127; int t = idx >> 7;
    int yh = t & 127;   t >>= 7;
    int cg = t & 15;    int b = t >> 4;
    float xv[9];
    #pragma unroll
    for (int ky = 0; ky < 3; ++ky) {
        int yy = yh + ky - 1;
        #pragma unroll
        for (int kx = 0; kx < 3; ++kx) {
            int xx = xw + kx - 1;
            xv[ky * 3 + kx] =
                ((unsigned)yy < 128u && (unsigned)xx < 128u)
                    ? ldm(x, b * HW + yy * WW + xx, bf) : 0.f;
        }
    }
    #pragma unroll
    for (int j = 0; j < 4; ++j) {
        int co = cg * 4 + j;
        float acc = ldm(bias, co, bf);
        #pragma unroll
        for (int k = 0; k < 9; ++k)
            acc = fmaf(ldm(w, co * 9 + k, bf), xv[k], acc);
        out[((size_t)(b * 64 + co) * HH + yh) * WW + xw] = fmaxf(acc, 0.f);
    }
}

// =====================================================================
// fused_mid: offconv(64->18) + deform + conv(64->32) + relu, all MFMA.
// Block = 64-px half-row, 4 waves; wave w owns px strip w*16..w*16+15.
// =====================================================================
__global__ __launch_bounds__(256) void fused_mid(
        const float* __restrict__ h1, const u16* __restrict__ btA,
        const u16* __restrict__ btB, const float* __restrict__ bo,
        const float* __restrict__ bd, u16* __restrict__ h2) {
    __shared__ u16 win[23296];      // [64ci][5*72+4pad] bf16 window
    __shared__ float aux[1280];     // offb[64][20] ; reused as cb u16[32][66]
    int tid = threadIdx.x;
    int lane = tid & 63, p = lane & 15, q = lane >> 4;
    int wv = __builtin_amdgcn_readfirstlane(tid >> 6);
    int bid = blockIdx.x;
    int hx = bid & 1, yh = (bid >> 1) & 127, b = bid >> 8;
    int xwb = hx * 64, bx = xwb - 4;
    int pxl = wv * 16 + p;
    const float* h1b = h1 + (size_t)b * 64 * HW;

    // ---- stage window: 64ci x 5rows x 72cols, f32 -> bf16 ----
    #pragma unroll 1
    for (int it = 0; it < 23; ++it) {
        int s = it * 256 + tid;
        if (s < 5760) {
            int ci = s / 90, rem = s % 90, row = rem / 18, c4 = rem % 18;
            int gy = yh - 2 + row, gc = bx + 4 * c4;
            u32 w0 = 0, w1 = 0;
            if ((unsigned)gy < 128u && (unsigned)gc < 128u) {
                float4 v = *(const float4*)(h1b + (size_t)ci * HW + gy * 128 + gc);
                w0 = (u32)f2bf(v.x) | ((u32)f2bf(v.y) << 16);
                w1 = (u32)f2bf(v.z) | ((u32)f2bf(v.w) << 16);
            }
            u32* dst = (u32*)&win[ci * 364 + row * 72 + c4 * 4];
            dst[0] = w0; dst[1] = w1;
        }
    }
    __syncthreads();

    // ---- phase A: offset conv as MFMA (K = kk*64+ci, 18 chunks) ----
    f32x4 a0 = {0.f, 0.f, 0.f, 0.f}, a1 = {0.f, 0.f, 0.f, 0.f};
    short8 nb0 = *(const short8*)(btA + p * 576 + 8 * q);
    short8 nb1 = *(const short8*)(btA + (16 + p) * 576 + 8 * q);
    #pragma unroll
    for (int c = 0; c < 18; ++c) {
        short8 b0 = nb0, b1 = nb1;
        if (c < 17) {
            nb0 = *(const short8*)(btA + p * 576 + 32 * (c + 1) + 8 * q);
            nb1 = *(const short8*)(btA + (16 + p) * 576 + 32 * (c + 1) + 8 * q);
        }
        const int kk = c >> 1, ky = kk / 3, kx = kk % 3;
        int adr = (((c & 1) << 5) + 8 * q) * 364 + (ky + 1) * 72 + (pxl + 3 + kx);
        short8 av;
        #pragma unroll
        for (int j = 0; j < 8; ++j) { av[j] = (short)win[adr]; adr += 364; }
        a0 = __builtin_amdgcn_mfma_f32_16x16x32_bf16(av, b0, a0, 0, 0, 0);
        a1 = __builtin_amdgcn_mfma_f32_16x16x32_bf16(av, b1, a1, 0, 0, 0);
        __builtin_amdgcn_sched_barrier(0);
    }
    #pragma unroll
    for (int r = 0; r < 4; ++r) {            // C: row=q*4+r, col=p
        int row = wv * 16 + q * 4 + r;
        aux[row * 20 + p] = a0[r] + bo[p];
        if (p < 2) aux[row * 20 + 16 + p] = a1[r] + bo[16 + p];
    }
    __syncthreads();

    // ---- geometry (per lane, for its A-row pixel) ----
    float wyA[9], wxA[9]; int pk[9];
    #pragma unroll
    for (int n = 0; n < 9; ++n) {
        float py  = aux[pxl * 20 + n]     + (float)(n / 3 - 1 + yh);
        float pxf = aux[pxl * 20 + 9 + n] + (float)(n % 3 - 1 + xwb + pxl);
        py  = fminf(fmaxf(py, 0.f), 127.f);
        pxf = fminf(fmaxf(pxf, 0.f), 127.f);
        float y0f = floorf(py), x0f = floorf(pxf);
        int y0 = (int)y0f, x0 = (int)x0f;
        int dy = (y0 < 127) ? 1 : 0, dx = (x0 < 127) ? 1 : 0;
        wyA[n] = py - y0f; wxA[n] = pxf - x0f;
        int slot = y0 - yh + 2, cix = x0 - bx;
        bool inw = slot >= 0 && slot + dy <= 4 && cix >= 0 && cix + dx < 72;
        pk[n] = (inw ? ((slot * 72 + cix) | 2048) : 0) | (dx << 9) | (dy << 10)
              | (x0 << 12) | (y0 << 19);
    }
    __syncthreads();

    // ---- phase B: deform GEMM as MFMA (K = n*64+ci, 18 chunks) ----
    f32x4 c0 = {0.f, 0.f, 0.f, 0.f}, c1 = {0.f, 0.f, 0.f, 0.f};
    nb0 = *(const short8*)(btB + p * 576 + 8 * q);
    nb1 = *(const short8*)(btB + (16 + p) * 576 + 8 * q);
    #pragma unroll
    for (int c = 0; c < 18; ++c) {
        short8 b0 = nb0, b1 = nb1;
        if (c < 17) {
            nb0 = *(const short8*)(btB + p * 576 + 32 * (c + 1) + 8 * q);
            nb1 = *(const short8*)(btB + (16 + p) * 576 + 32 * (c + 1) + 8 * q);
        }
        const int n = c >> 1;
        int ci0 = ((c & 1) << 5) + 8 * q;
        int pp = pk[n];
        float wy = wyA[n], wx = wxA[n];
        short8 av;
        if (pp & 2048) {
            int adr = ci0 * 364 + (pp & 511);
            int dxo = (pp >> 9) & 1, dyo = ((pp >> 10) & 1) * 72;
            #pragma unroll
            for (int j = 0; j < 8; ++j) {
                float v00 = bf2f(win[adr]),       v01 = bf2f(win[adr + dxo]);
                float v10 = bf2f(win[adr + dyo]), v11 = bf2f(win[adr + dyo + dxo]);
                float top = fmaf(wx, v01 - v00, v00);
                float bot = fmaf(wx, v11 - v10, v10);
                av[j] = (short)f2bf(fmaf(wy, bot - top, top));
                adr += 364;
            }
        } else {           // out-of-window fallback (general offsets)
            const float* fp = h1b + (size_t)ci0 * HW
                            + ((pp >> 19) & 127) * 128 + ((pp >> 12) & 127);
            int dxo = (pp >> 9) & 1, dyo = ((pp >> 10) & 1) * 128;
            #pragma unroll
            for (int j = 0; j < 8; ++j) {
                float v00 = fp[0], v01 = fp[dxo], v10 = fp[dyo], v11 = fp[dyo + dxo];
                float top = fmaf(wx, v01 - v00, v00);
                float bot = fmaf(wx, v11 - v10, v10);
                av[j] = (short)f2bf(fmaf(wy, bot - top, top));
                fp += HW;
            }
        }
        c0 = __builtin_amdgcn_mfma_f32_16x16x32_bf16(av, b0, c0, 0, 0, 0);
        c1 = __builtin_amdgcn_mfma_f32_16x16x32_bf16(av, b1, c1, 0, 0, 0);
        __builtin_amdgcn_sched_barrier(0);
    }
    // ---- C -> LDS bounce (bf16) -> coalesced h2 stores ----
    u16* cb = (u16*)aux;
    #pragma unroll
    for (int r = 0; r < 4; ++r) {
        int px = wv * 16 + q * 4 + r;
        cb[p * 66 + px]        = f2bf(fmaxf(c0[r] + bd[p], 0.f));
        cb[(16 + p) * 66 + px] = f2bf(fmaxf(c1[r] + bd[16 + p], 0.f));
    }
    __syncthreads();
    int px = tid & 63, cg = tid >> 6;
    #pragma unroll
    for (int i = 0; i < 8; ++i) {
        int co = cg * 8 + i;
        h2[(size_t)(b * 32 + co) * HW + yh * 128 + xwb + px] = cb[co * 66 + px];
    }
}

// =====================================================================
// fused_final: offconv(32->18) + deform + conv(32->4) + pixel shuffle.
// Same structure, CIN=32 (9 chunks), h2 is bf16.
// =====================================================================
__global__ __launch_bounds__(256) void fused_final(
        const u16* __restrict__ h2, const u16* __restrict__ btA,
        const u16* __restrict__ btB, const float* __restrict__ bo,
        const float* __restrict__ bd, const u32* __restrict__ xu,
        float* __restrict__ outf, u32* __restrict__ outb) {
    __shared__ u16 win[11648];      // [32ci][5*72+4pad]
    __shared__ float aux[1280];     // offb[64][20] ; reused as ob[64][5]
    bool bf = wave_flag(xu);
    int tid = threadIdx.x;
    int lane = tid & 63, p = lane & 15, q = lane >> 4;
    int wv = __builtin_amdgcn_readfirstlane(tid >> 6);
    int bid = blockIdx.x;
    int hx = bid & 1, yh = (bid >> 1) & 127, b = bid >> 8;
    int xwb = hx * 64, bx = xwb - 4;
    int pxl = wv * 16 + p;
    const u16* h2b = h2 + (size_t)b * 32 * HW;

    // ---- stage window: 32ci x 5rows x 72cols, bf16 copy ----
    #pragma unroll 1
    for (int it = 0; it < 12; ++it) {
        int s = it * 256 + tid;
        if (s < 2880) {
            int ci = s / 90, rem = s % 90, row = rem / 18, c4 = rem % 18;
            int gy = yh - 2 + row, gc = bx + 4 * c4;
            u32 w0 = 0, w1 = 0;
            if ((unsigned)gy < 128u && (unsigned)gc < 128u) {
                const u32* src = (const u32*)(h2b + (size_t)ci * HW + gy * 128 + gc);
                w0 = src[0]; w1 = src[1];
            }
            u32* dst = (u32*)&win[ci * 364 + row * 72 + c4 * 4];
            dst[0] = w0; dst[1] = w1;
        }
    }
    __syncthreads();

    // ---- phase A (K = kk*32+ci, 9 chunks) ----
    f32x4 a0 = {0.f, 0.f, 0.f, 0.f}, a1 = {0.f, 0.f, 0.f, 0.f};
    short8 nb0 = *(const short8*)(btA + p * 288 + 8 * q);
    short8 nb1 = *(const short8*)(btA + (16 + p) * 288 + 8 * q);
    #pragma unroll
    for (int c = 0; c < 9; ++c) {
        short8 b0 = nb0, b1 = nb1;
        if (c < 8) {
            nb0 = *(const short8*)(btA + p * 288 + 32 * (c + 1) + 8 * q);
            nb1 = *(const short8*)(btA + (16 + p) * 288 + 32 * (c + 1) + 8 * q);
        }
        const int ky = c / 3, kx = c % 3;
        int adr = 8 * q * 364 + (ky + 1) * 72 + (pxl + 3 + kx);
        short8 av;
        #pragma unroll
        for (int j = 0; j < 8; ++j) { av[j] = (short)win[adr]; adr += 364; }
        a0 = __builtin_amdgcn_mfma_f32_16x16x32_bf16(av, b0, a0, 0, 0, 0);
        a1 = __builtin_amdgcn_mfma_f32_16x16x32_bf16(av, b1, a1, 0, 0, 0);
        __builtin_amdgcn_sched_barrier(0);
    }
    #pragma unroll
    for (int r = 0; r < 4; ++r) {
        int row = wv * 16 + q * 4 + r;
        aux[row * 20 + p] = a0[r] + bo[p];
        if (p < 2) aux[row * 20 + 16 + p] = a1[r] + bo[16 + p];
    }
    __syncthreads();

    // ---- geometry ----
    float wyA[9], wxA[9]; int pk[9];
    #pragma unroll
    for (int n = 0; n < 9; ++n) {
        float py  = aux[pxl * 20 + n]     + (float)(n / 3 - 1 + yh);
        float pxf = aux[pxl * 20 + 9 + n] + (float)(n % 3 - 1 + xwb + pxl);
        py  = fminf(fmaxf(py, 0.f), 127.f);
        pxf = fminf(fmaxf(pxf, 0.f), 127.f);
        float y0f = floorf(py), x0f = floorf(pxf);
        int y0 = (int)y0f, x0 = (int)x0f;
        int dy = (y0 < 127) ? 1 : 0, dx = (x0 < 127) ? 1 : 0;
        wyA[n] = py - y0f; wxA[n] = pxf - x0f;
        int slot = y0 - yh + 2, cix = x0 - bx;
        bool inw = slot >= 0 && slot + dy <= 4 && cix >= 0 && cix + dx < 72;
        pk[n] = (inw ? ((slot * 72 + cix) | 2048) : 0) | (dx << 9) | (dy << 10)
              | (x0 << 12) | (y0 << 19);
    }
    __syncthreads();

    // ---- phase B (K = n*32+ci, 9 chunks, single co-tile) ----
    f32x4 c0 = {0.f, 0.f, 0.f, 0.f};
    nb0 = *(const short8*)(btB + p * 288 + 8 * q);
    #pragma unroll
    for (int c = 0; c < 9; ++c) {
        short8 b0 = nb0;
        if (c < 8) nb0 = *(const short8*)(btB + p * 288 + 32 * (c + 1) + 8 * q);
        const int n = c;
        int ci0 = 8 * q;
        int pp = pk[n];
        float wy = wyA[n], wx = wxA[n];
        short8 av;
        if (pp & 2048) {
            int adr = ci0 * 364 + (pp & 511);
            int dxo = (pp >> 9) & 1, dyo = ((pp >> 10) & 1) * 72;
            #pragma unroll
            for (int j = 0; j < 8; ++j) {
                float v00 = bf2f(win[adr]),       v01 = bf2f(win[adr + dxo]);
                float v10 = bf2f(win[adr + dyo]), v11 = bf2f(win[adr + dyo + dxo]);
                float top = fmaf(wx, v01 - v00, v00);
                float bot = fmaf(wx, v11 - v10, v10);
                av[j] = (short)f2bf(fmaf(wy, bot - top, top));
                adr += 364;
            }
        } else {
            const u16* fp = h2b + (size_t)ci0 * HW
                          + ((pp >> 19) & 127) * 128 + ((pp >> 12) & 127);
            int dxo = (pp >> 9) & 1, dyo = ((pp >> 10) & 1) * 128;
            #pragma unroll
            for (int j = 0; j < 8; ++j) {
                float v00 = bf2f(fp[0]),  v01 = bf2f(fp[dxo]);
                float v10 = bf2f(fp[dyo]), v11 = bf2f(fp[dyo + dxo]);
                float top = fmaf(wx, v01 - v00, v00);
                float bot = fmaf(wx, v11 - v10, v10);
                av[j] = (short)f2bf(fmaf(wy, bot - top, top));
                fp += HW;
            }
        }
        c0 = __builtin_amdgcn_mfma_f32_16x16x32_bf16(av, b0, c0, 0, 0, 0);
        __builtin_amdgcn_sched_barrier(0);
    }
    // ---- output bounce + pixel shuffle ----
    if (p < 4) {
        #pragma unroll
        for (int r = 0; r < 4; ++r)
            aux[(wv * 16 + q * 4 + r) * 5 + p] = c0[r] + bd[p];
    }
    __syncthreads();
    if (tid < 64) {
        float o0 = aux[tid * 5 + 0], o1 = aux[tid * 5 + 1];
        float o2 = aux[tid * 5 + 2], o3 = aux[tid * 5 + 3];
        int xw = xwb + tid;
        if (bf) {
            u32 p0 = ((u32)f2bf(o1) << 16) | (u32)f2bf(o0);
            u32 p1 = ((u32)f2bf(o3) << 16) | (u32)f2bf(o2);
            outb[(size_t)(b * 256 + 2 * yh) * 128 + xw]     = p0;
            outb[(size_t)(b * 256 + 2 * yh + 1) * 128 + xw] = p1;
        } else {
            size_t r0 = (size_t)(b * 256 + 2 * yh) * 256 + 2 * xw;
            outf[r0]       = o0;
            outf[r0 + 1]   = o1;
            outf[r0 + 256] = o2;
            outf[r0 + 257] = o3;
        }
    }
}

extern "C" void kernel_launch(void* const* d_in, const int* in_sizes, int n_in,
                              void* d_out, int out_size, void* d_ws, size_t ws_size,
                              hipStream_t stream) {
    float* ws = (float*)d_ws;
    const u32* xu = (const u32*)d_in[0];
    prep_weights<<<72, 256, 0, stream>>>(xu, d_in[3], d_in[4], d_in[5], d_in[6],
                                         d_in[7], d_in[8], d_in[9], d_in[10], ws);
    conv1_kernel<<<4096, 256, 0, stream>>>(xu, d_in[0], d_in[1], d_in[2], ws + O_H1);
    fused_mid<<<1024, 256, 0, stream>>>(
        ws + O_H1, (const u16*)(ws + O_BTA2), (const u16*)(ws + O_BTB2),
        ws + O_BO2, ws + O_B2, (u16*)(ws + O_H2));
    fused_final<<<1024, 256, 0, stream>>>(
        (const u16*)(ws + O_H2), (const u16*)(ws + O_BTA3),
        (const u16*)(ws + O_BTB3), ws + O_BO3, ws + O_B3,
        xu, (float*)d_out, (u32*)d_out);
}